// Round 6
// baseline (258.385 us; speedup 1.0000x reference)
//
#include <hip/hip_runtime.h>

#define NUM_NODES 100000
#define OUT_CH 32
#define NUM_EDGES 3200000

// buckets of 128 raw rows
#define RPB 128
#define NB 782                  // data buckets (raw row <= 99999 -> bucket <= 781)
#define NBG 783                 // gather covers raw rows 0..100223 (safe: rmin ~0)
#define CAP2 5120               // mean 4096, sigma ~64 -> +16 sigma
#define TPB 512
// transpose: 128-col tiles
#define TRB 782
// binning: 512 slices of 6250 edges
#define BINS 512
#define SLICE 6250

static __device__ __forceinline__ unsigned short f32_to_bf16_rne(float f) {
    unsigned u = __float_as_uint(f);
    unsigned r = u + 0x7FFFu + ((u >> 16) & 1u);
    return (unsigned short)(r >> 16);
}
static __device__ __forceinline__ float bf16_to_f32(unsigned short h) {
    return __uint_as_float(((unsigned)h) << 16);
}

struct TransLds { float tile[32][129]; };                    // 16512 B
struct BinLds   { int cnt[NB]; int cur[NB]; int wm[8]; };    // 6288 B
struct GatherLds {
    int cnt2[RPB * 8]; int cur2[RPB * 8];
    int rowstart[RPB]; int rowcnt[RPB]; int scn[RPB];
    int lcol[CAP2]; int wmin[8];
};                                                           // 30240 B
union AllLds { TransLds tr; BinLds bn; GatherLds g; };

// Device-scope grid barrier with EXPLICIT agent fences.
// Round-4's cg::grid::sync() left stale cross-XCD L2 lines (bin bytes differ
// per iteration -> one stale 64B line = the observed 5.5e-2 absmax). Here:
// release-RMW arrive (flushes XCD L2), relaxed agent-scope spin (reads at the
// coherence point, no per-poll invalidate), then one acquire agent fence
// (invalidates L1+L2) before any cross-phase data is read.
static __device__ __forceinline__ void grid_barrier(int* bar, int t) {
    __syncthreads();
    if (t == 0) {
        __hip_atomic_fetch_add(bar, 1, __ATOMIC_RELEASE, __HIP_MEMORY_SCOPE_AGENT);
        while (__hip_atomic_load(bar, __ATOMIC_RELAXED, __HIP_MEMORY_SCOPE_AGENT) < (int)gridDim.x)
            __builtin_amdgcn_s_sleep(2);
        __builtin_amdgcn_fence(__ATOMIC_ACQUIRE, "agent");
    }
    __syncthreads();
}

__global__ void __launch_bounds__(TPB, 8)
link_all(const float* __restrict__ W, ushort4* Wt,
         const int* __restrict__ edge, int* partmin,
         int* bcount, unsigned int* bin,
         const float* __restrict__ bv, float* __restrict__ out,
         int* bar) {
    __shared__ AllLds u;
    int bk   = blockIdx.x;
    int t    = threadIdx.x;
    int grid = gridDim.x;
    int tb0  = (grid >= BINS + 256) ? BINS : (grid >> 1);   // bin blocks

    // ---------------- P1: bin slices (bk < tb0)  ||  transpose W (bk >= tb0) ----------------
    // bucket = raw_row >> 7 (no rmin dependency); entry = (raw&127)<<17 | col.
    if (bk < tb0) {
        for (int sl = bk; sl < BINS; sl += tb0) {
            for (int i = t; i < NB; i += TPB) u.bn.cnt[i] = 0;
            __syncthreads();
            int base = sl * SLICE;
            int rm = 0x7fffffff;
            // sweep A: count per bucket + row min (slice becomes L2-hot)
            for (int o = t; o < SLICE; o += TPB) {
                int r = edge[base + o];
                rm = min(rm, r);
                atomicAdd(&u.bn.cnt[r >> 7], 1);
            }
            #pragma unroll
            for (int off = 32; off > 0; off >>= 1) rm = min(rm, __shfl_down(rm, off, 64));
            if ((t & 63) == 0) u.bn.wm[t >> 6] = rm;
            __syncthreads();                    // cnt + wm complete
            if (t == 0) {
                int m = u.bn.wm[0];
                #pragma unroll
                for (int w = 1; w < TPB / 64; w++) m = min(m, u.bn.wm[w]);
                partmin[sl] = m;                // distinct address per slice
            }
            // one global reservation per (slice, bucket)
            for (int i = t; i < NB; i += TPB)
                u.bn.cur[i] = u.bn.cnt[i] ? atomicAdd(&bcount[i], u.bn.cnt[i]) : 0;
            __syncthreads();
            // sweep B: re-read (L2-hot) and scatter
            for (int o = t; o < SLICE; o += TPB) {
                int r = edge[base + o];
                int c = edge[NUM_EDGES + base + o];
                int b = r >> 7;
                int pos = atomicAdd(&u.bn.cur[b], 1);
                if (pos < CAP2)
                    bin[(size_t)b * CAP2 + pos] = ((unsigned)(r & 127) << 17) | (unsigned)c;
            }
            __syncthreads();
        }
    } else {
        int tstride = grid - tb0;
        for (int tb = bk - tb0; tb < TRB; tb += tstride) {
            int tx = t & 127, ty = t >> 7;      // 128 x 4 threads, 8 sweeps
            int colBase = tb * 128;
            int col = colBase + tx;
            if (col < NUM_NODES) {
                #pragma unroll
                for (int k = 0; k < 8; k++) {
                    int c = ty + 4 * k;
                    u.tr.tile[c][tx] = W[(size_t)c * NUM_NODES + col];
                }
            }
            __syncthreads();
            #pragma unroll
            for (int s = 0; s < 2; s++) {
                int o  = s * TPB + t;           // 0..1023
                int lc = o >> 3, q = o & 7;
                int ocol = colBase + lc;
                if (ocol < NUM_NODES) {
                    ushort4 w;
                    w.x = f32_to_bf16_rne(u.tr.tile[q * 4 + 0][lc]);
                    w.y = f32_to_bf16_rne(u.tr.tile[q * 4 + 1][lc]);
                    w.z = f32_to_bf16_rne(u.tr.tile[q * 4 + 2][lc]);
                    w.w = f32_to_bf16_rne(u.tr.tile[q * 4 + 3][lc]);
                    Wt[(size_t)ocol * 8 + q] = w;
                }
            }
            __syncthreads();
        }
    }
    grid_barrier(bar, t);

    // ---------------- P2: per-bucket LDS CSR + 2-row, 2x k-batched bf16 gather ----------------
    int pm = (t < BINS) ? partmin[t] : 0x7fffffff;   // BINS == TPB
    #pragma unroll
    for (int off = 32; off > 0; off >>= 1) pm = min(pm, __shfl_down(pm, off, 64));
    if ((t & 63) == 0) u.g.wmin[t >> 6] = pm;
    __syncthreads();
    int rmin = u.g.wmin[0];
    #pragma unroll
    for (int w = 1; w < TPB / 64; w++) rmin = min(rmin, u.g.wmin[w]);
    __syncthreads();

    for (int gb = bk; gb < NBG; gb += grid) {
        int n = (gb < NB) ? bcount[gb] : 0;
        if (n > CAP2) n = CAP2;
        const unsigned int* mybin = bin + (size_t)gb * CAP2;

        for (int i = t; i < RPB * 8; i += TPB) u.g.cnt2[i] = 0;
        __syncthreads();

        // pass 1: count per (row, col-seg)
        for (int i = t; i < n; i += TPB) {
            unsigned int p = mybin[i];
            int lr  = p >> 17;
            int seg = (p & 0x1FFFF) >> 14;
            atomicAdd(&u.g.cnt2[(lr << 3) | seg], 1);
        }
        __syncthreads();

        if (t < RPB) {
            int s = 0;
            #pragma unroll
            for (int k = 0; k < 8; k++) s += u.g.cnt2[(t << 3) | k];
            u.g.rowcnt[t] = s;
            u.g.scn[t] = s;
        }
        __syncthreads();
        for (int off = 1; off < RPB; off <<= 1) {
            int v = (t < RPB && t >= off) ? u.g.scn[t - off] : 0;
            __syncthreads();
            if (t < RPB) u.g.scn[t] += v;
            __syncthreads();
        }
        if (t < RPB) {
            int rs = u.g.scn[t] - u.g.rowcnt[t];
            u.g.rowstart[t] = rs;
            int run = rs;
            #pragma unroll
            for (int k = 0; k < 8; k++) { u.g.cur2[(t << 3) | k] = run; run += u.g.cnt2[(t << 3) | k]; }
        }
        __syncthreads();

        // pass 2: scatter cols into LDS CSR (rows contiguous, segs ascending)
        for (int i = t; i < n; i += TPB) {
            unsigned int p = mybin[i];
            int lr = p >> 17;
            int c  = p & 0x1FFFF;
            int pos = atomicAdd(&u.g.cur2[(lr << 3) | (c >> 14)], 1);
            u.g.lcol[pos] = c;
        }
        __syncthreads();

        // gather-sum: 8 lanes/row, 2 rows/thread, 2x k-batch (4 loads in flight)
        int g   = t >> 3;       // 0..63
        int sub = t & 7;
        float4 bias = ((const float4*)bv)[sub];
        int lrA = g, lrB = g + 64;
        int outA = gb * RPB + lrA - rmin;
        int outB = gb * RPB + lrB - rmin;
        bool vA = (unsigned)outA < NUM_NODES;
        bool vB = (unsigned)outB < NUM_NODES;
        int iA = u.g.rowstart[lrA], eA = iA + u.g.rowcnt[lrA];
        int iB = u.g.rowstart[lrB], eB = iB + u.g.rowcnt[lrB];
        if (!vA) { iA = eA = 0; }
        if (!vB) { iB = eB = 0; }
        float4 accA = bias, accB = bias;
        int nPair = min(eA - iA, eB - iB);
        int k = 0;
        for (; k + 2 <= nPair; k += 2) {
            int cA0 = u.g.lcol[iA + k],     cB0 = u.g.lcol[iB + k];
            int cA1 = u.g.lcol[iA + k + 1], cB1 = u.g.lcol[iB + k + 1];
            ushort4 wA0 = Wt[(size_t)cA0 * 8 + sub];
            ushort4 wB0 = Wt[(size_t)cB0 * 8 + sub];
            ushort4 wA1 = Wt[(size_t)cA1 * 8 + sub];
            ushort4 wB1 = Wt[(size_t)cB1 * 8 + sub];
            accA.x += bf16_to_f32(wA0.x) + bf16_to_f32(wA1.x);
            accA.y += bf16_to_f32(wA0.y) + bf16_to_f32(wA1.y);
            accA.z += bf16_to_f32(wA0.z) + bf16_to_f32(wA1.z);
            accA.w += bf16_to_f32(wA0.w) + bf16_to_f32(wA1.w);
            accB.x += bf16_to_f32(wB0.x) + bf16_to_f32(wB1.x);
            accB.y += bf16_to_f32(wB0.y) + bf16_to_f32(wB1.y);
            accB.z += bf16_to_f32(wB0.z) + bf16_to_f32(wB1.z);
            accB.w += bf16_to_f32(wB0.w) + bf16_to_f32(wB1.w);
        }
        for (; k < nPair; k++) {
            ushort4 wA = Wt[(size_t)u.g.lcol[iA + k] * 8 + sub];
            ushort4 wB = Wt[(size_t)u.g.lcol[iB + k] * 8 + sub];
            accA.x += bf16_to_f32(wA.x); accA.y += bf16_to_f32(wA.y);
            accA.z += bf16_to_f32(wA.z); accA.w += bf16_to_f32(wA.w);
            accB.x += bf16_to_f32(wB.x); accB.y += bf16_to_f32(wB.y);
            accB.z += bf16_to_f32(wB.z); accB.w += bf16_to_f32(wB.w);
        }
        iA += nPair; iB += nPair;
        for (; iA < eA; iA++) {
            ushort4 w = Wt[(size_t)u.g.lcol[iA] * 8 + sub];
            accA.x += bf16_to_f32(w.x); accA.y += bf16_to_f32(w.y);
            accA.z += bf16_to_f32(w.z); accA.w += bf16_to_f32(w.w);
        }
        for (; iB < eB; iB++) {
            ushort4 w = Wt[(size_t)u.g.lcol[iB] * 8 + sub];
            accB.x += bf16_to_f32(w.x); accB.y += bf16_to_f32(w.y);
            accB.z += bf16_to_f32(w.z); accB.w += bf16_to_f32(w.w);
        }
        if (vA) ((float4*)out)[(size_t)outA * 8 + sub] = accA;
        if (vB) ((float4*)out)[(size_t)outB * 8 + sub] = accB;
        __syncthreads();                        // LDS reuse if this block loops
    }
}

extern "C" void kernel_launch(void* const* d_in, const int* in_sizes, int n_in,
                              void* d_out, int out_size, void* d_ws, size_t ws_size,
                              hipStream_t stream) {
    const int*   edge = (const int*)d_in[0];     // [2, NUM_EDGES] int32
    const float* W    = (const float*)d_in[1];   // [32, NUM_NODES]
    const float* b    = (const float*)d_in[2];   // [32]
    float* out = (float*)d_out;                  // [NUM_NODES, 32]

    // workspace: bar @0 | partmin @1024 (2048B) | bcount @4096 (3132B) | Wt @8192 (6.4MB) | bin @6422528 (16MB)
    char* ws = (char*)d_ws;
    int*          bar     = (int*)ws;
    int*          partmin = (int*)(ws + 1024);
    int*          bcount  = (int*)(ws + 4096);
    ushort4*      Wt      = (ushort4*)(ws + 8192);
    unsigned int* bin     = (unsigned int*)(ws + 6422528);

    static int bpc = 0;
    if (bpc == 0) {
        hipOccupancyMaxActiveBlocksPerMultiprocessor(&bpc, link_all, TPB, 0);
        if (bpc < 1) bpc = 1;
        if (bpc > 4) bpc = 4;
    }
    int grid = bpc * 256;

    hipMemsetAsync(ws, 0, 7232, stream);         // bar + partmin + bcount
    void* args[] = { (void*)&W, (void*)&Wt, (void*)&edge, (void*)&partmin,
                     (void*)&bcount, (void*)&bin, (void*)&b, (void*)&out,
                     (void*)&bar };
    hipLaunchCooperativeKernel((const void*)link_all, dim3(grid), dim3(TPB),
                               args, 0, stream);
}

// Round 7
// 158.864 us; speedup vs baseline: 1.6265x; 1.6265x over previous
//
#include <hip/hip_runtime.h>

#define NUM_NODES 100000
#define OUT_CH 32
#define NUM_EDGES 3200000

// fine buckets: 128 raw rows each
#define RPB 128
#define NB 782                  // buckets with data: raw row <= 99999 -> bucket <= 781
#define NBG 783                 // bcount array size (zeroed)
#define CAP2 5120               // mean 4096, sigma ~64 -> +16 sigma
// fused front-end (uniform 1024-thread blocks) -- EXACT round-3 form (measured <=48us)
#define FTPB 1024
#define TRB 782                 // 128-col transpose tiles: ceil(100000/128)
#define BINB 250
#define TILE 12800              // 250*12800 = 3.2M; runs/(block,bucket) ~16 -> full 64B lines
#define KPT 13                  // ceil(TILE/FTPB)
// gather: 2 blocks per bucket (64 rows each), all co-resident
#define GTPB 256
#define CAPH 2560               // per-half capacity (mean 2048)
#define GGRID 1568              // 98*16: bucket=((bk>>4)<<3)|(bk&7), half=(bk>>3)&1

static __device__ __forceinline__ unsigned short f32_to_bf16_rne(float f) {
    unsigned u = __float_as_uint(f);
    unsigned r = u + 0x7FFFu + ((u >> 16) & 1u);
    return (unsigned short)(r >> 16);
}
static __device__ __forceinline__ float bf16_to_f32(unsigned short h) {
    return __uint_as_float(((unsigned)h) << 16);
}

// ---------------- fused front-end: transpose W->Wt(bf16) || bin edges by RAW row ----------------
// byte-identical to round-3's fused_pre (register-array binning), which measured <=48us.
__global__ void __launch_bounds__(FTPB)
fused_pre(const float* __restrict__ W, ushort4* __restrict__ Wt,
          const int* __restrict__ edge, int* __restrict__ partmin,
          int* __restrict__ bcount, unsigned int* __restrict__ bin) {
    int bk = blockIdx.x;
    int t  = threadIdx.x;
    if (bk < TRB) {
        __shared__ float tile[32][129];
        int tx = t & 127, ty = t >> 7;          // 128 x 8 threads, 4 sweeps
        int colBase = bk * 128;
        int col = colBase + tx;
        if (col < NUM_NODES) {
            #pragma unroll
            for (int k = 0; k < 4; k++) {
                int c = ty + 8 * k;
                tile[c][tx] = W[(size_t)c * NUM_NODES + col];
            }
        }
        __syncthreads();
        int lc = t >> 3, q = t & 7;             // ushort4 store (8B), fully coalesced
        int ocol = colBase + lc;
        if (ocol < NUM_NODES) {
            ushort4 o;
            o.x = f32_to_bf16_rne(tile[q * 4 + 0][lc]);
            o.y = f32_to_bf16_rne(tile[q * 4 + 1][lc]);
            o.z = f32_to_bf16_rne(tile[q * 4 + 2][lc]);
            o.w = f32_to_bf16_rne(tile[q * 4 + 3][lc]);
            Wt[(size_t)ocol * 8 + q] = o;
        }
    } else {
        int mb = bk - TRB;
        __shared__ int cnt[NB];
        __shared__ int cur[NB];
        __shared__ int wm[16];
        for (int i = t; i < NB; i += FTPB) cnt[i] = 0;
        __syncthreads();
        int base = mb * TILE;
        unsigned int ent[KPT];
        int bb[KPT];
        int rm = 0x7fffffff;
        #pragma unroll
        for (int k = 0; k < KPT; k++) {
            int o = k * FTPB + t;
            bb[k] = -1;
            if (o < TILE) {
                int e = base + o;               // coalesced
                int r = edge[e];
                int c = edge[NUM_EDGES + e];
                rm = min(rm, r);
                int b = r >> 7;
                bb[k]  = b;
                ent[k] = ((unsigned int)(r & 127) << 17) | (unsigned int)c;
                atomicAdd(&cnt[b], 1);
            }
        }
        #pragma unroll
        for (int off = 32; off > 0; off >>= 1) rm = min(rm, __shfl_down(rm, off, 64));
        if ((t & 63) == 0) wm[t >> 6] = rm;
        __syncthreads();                        // cnt + wm complete
        if (t == 0) {
            int m = wm[0];
            #pragma unroll
            for (int w = 1; w < 16; w++) m = min(m, wm[w]);
            partmin[mb] = m;                    // plain store, distinct address per block
        }
        // one global reservation per (block, bucket): runs ~16 -> full 64B lines
        for (int i = t; i < NB; i += FTPB)
            cur[i] = cnt[i] ? atomicAdd(&bcount[i], cnt[i]) : 0;
        __syncthreads();
        #pragma unroll
        for (int k = 0; k < KPT; k++) {
            if (bb[k] >= 0) {
                int pos = atomicAdd(&cur[bb[k]], 1);
                if (pos < CAP2) bin[(size_t)bb[k] * CAP2 + pos] = ent[k];
            }
        }
    }
}

// ---------------- half-bucket LDS CSR + 2-row, 4x k-batched bf16 gather ----------------
// Two blocks per bucket (row bit-6 filter); blocks pairing a bucket are 8 apart in
// blockIdx (likely same XCD under round-robin dispatch -> shared L2 for the bin reads).
__global__ void __launch_bounds__(GTPB)
bucket_gather(const unsigned int* __restrict__ bin, const int* __restrict__ bcount,
              const int* __restrict__ partmin,
              const ushort4* __restrict__ Wt, const float* __restrict__ b,
              float* __restrict__ out) {
    __shared__ int cnt2[64 * 8];       // (localrow, col>>14) counters
    __shared__ int cur2[64 * 8];
    __shared__ int rowstart[64];
    __shared__ int rowcnt[64];
    __shared__ int scn[64];
    __shared__ int lcol[CAPH];
    __shared__ int wmin[4];
    __shared__ int rminS;

    int t  = threadIdx.x;
    int bk = blockIdx.x;
    int gb   = ((bk >> 4) << 3) | (bk & 7);   // bucket 0..783
    int hbit = ((bk >> 3) & 1) << 6;          // 0 or 64

    // reduce the 250 per-block row-mins (overlapped with setup)
    int pm = (t < BINB) ? partmin[t] : 0x7fffffff;
    #pragma unroll
    for (int off = 32; off > 0; off >>= 1) pm = min(pm, __shfl_down(pm, off, 64));
    if ((t & 63) == 0) wmin[t >> 6] = pm;

    int n = (gb < NB) ? bcount[gb] : 0;
    if (n > CAP2) n = CAP2;
    const unsigned int* mybin = bin + (size_t)gb * CAP2;

    for (int i = t; i < 64 * 8; i += GTPB) cnt2[i] = 0;
    __syncthreads();
    if (t == 0)
        rminS = min(min(wmin[0], wmin[1]), min(wmin[2], wmin[3]));

    // pass 1: count per (localrow, seg) for this half
    for (int i = t; i < n; i += GTPB) {
        unsigned int p = mybin[i];
        int lr = p >> 17;
        if ((lr & 64) == hbit) {
            int seg = (p & 0x1FFFF) >> 14;
            atomicAdd(&cnt2[((lr & 63) << 3) | seg], 1);
        }
    }
    __syncthreads();

    if (t < 64) {
        int s = 0;
        #pragma unroll
        for (int k = 0; k < 8; k++) s += cnt2[(t << 3) | k];
        rowcnt[t] = s;
        scn[t] = s;
    }
    __syncthreads();
    // inclusive scan over 64 row totals
    for (int off = 1; off < 64; off <<= 1) {
        int v = (t < 64 && t >= off) ? scn[t - off] : 0;
        __syncthreads();
        if (t < 64) scn[t] += v;
        __syncthreads();
    }
    if (t < 64) {
        int rs = scn[t] - rowcnt[t];
        rowstart[t] = rs;
        int run = rs;
        #pragma unroll
        for (int k = 0; k < 8; k++) { cur2[(t << 3) | k] = run; run += cnt2[(t << 3) | k]; }
    }
    __syncthreads();

    // pass 2: scatter cols into LDS CSR (rows contiguous, segs ascending within row)
    for (int i = t; i < n; i += GTPB) {
        unsigned int p = mybin[i];
        int lr = p >> 17;
        if ((lr & 64) == hbit) {
            int c = p & 0x1FFFF;
            int pos = atomicAdd(&cur2[((lr & 63) << 3) | (c >> 14)], 1);
            lcol[pos] = c;
        }
    }
    __syncthreads();

    // gather-sum: 8 lanes/row, 2 rows/thread, 4x k-batch (8 loads in flight)
    int g   = t >> 3;       // 0..31
    int sub = t & 7;
    float4 bias = ((const float4*)b)[sub];
    int rmin = rminS;
    int rowbase = gb * RPB + hbit;
    int outA = rowbase + g - rmin;
    int outB = rowbase + g + 32 - rmin;
    bool vA = (unsigned)outA < NUM_NODES;
    bool vB = (unsigned)outB < NUM_NODES;
    int iA = rowstart[g],      eA = iA + rowcnt[g];
    int iB = rowstart[g + 32], eB = iB + rowcnt[g + 32];
    if (!vA) { iA = eA = 0; }
    if (!vB) { iB = eB = 0; }
    float4 accA = bias, accB = bias;
    int nPair = min(eA - iA, eB - iB);
    int k = 0;
    for (; k + 4 <= nPair; k += 4) {
        int cA0 = lcol[iA + k],     cA1 = lcol[iA + k + 1];
        int cA2 = lcol[iA + k + 2], cA3 = lcol[iA + k + 3];
        int cB0 = lcol[iB + k],     cB1 = lcol[iB + k + 1];
        int cB2 = lcol[iB + k + 2], cB3 = lcol[iB + k + 3];
        ushort4 a0 = Wt[(size_t)cA0 * 8 + sub];
        ushort4 a1 = Wt[(size_t)cA1 * 8 + sub];
        ushort4 a2 = Wt[(size_t)cA2 * 8 + sub];
        ushort4 a3 = Wt[(size_t)cA3 * 8 + sub];
        ushort4 b0 = Wt[(size_t)cB0 * 8 + sub];
        ushort4 b1 = Wt[(size_t)cB1 * 8 + sub];
        ushort4 b2 = Wt[(size_t)cB2 * 8 + sub];
        ushort4 b3 = Wt[(size_t)cB3 * 8 + sub];
        accA.x += (bf16_to_f32(a0.x) + bf16_to_f32(a1.x)) + (bf16_to_f32(a2.x) + bf16_to_f32(a3.x));
        accA.y += (bf16_to_f32(a0.y) + bf16_to_f32(a1.y)) + (bf16_to_f32(a2.y) + bf16_to_f32(a3.y));
        accA.z += (bf16_to_f32(a0.z) + bf16_to_f32(a1.z)) + (bf16_to_f32(a2.z) + bf16_to_f32(a3.z));
        accA.w += (bf16_to_f32(a0.w) + bf16_to_f32(a1.w)) + (bf16_to_f32(a2.w) + bf16_to_f32(a3.w));
        accB.x += (bf16_to_f32(b0.x) + bf16_to_f32(b1.x)) + (bf16_to_f32(b2.x) + bf16_to_f32(b3.x));
        accB.y += (bf16_to_f32(b0.y) + bf16_to_f32(b1.y)) + (bf16_to_f32(b2.y) + bf16_to_f32(b3.y));
        accB.z += (bf16_to_f32(b0.z) + bf16_to_f32(b1.z)) + (bf16_to_f32(b2.z) + bf16_to_f32(b3.z));
        accB.w += (bf16_to_f32(b0.w) + bf16_to_f32(b1.w)) + (bf16_to_f32(b2.w) + bf16_to_f32(b3.w));
    }
    for (; k < nPair; k++) {
        ushort4 wA = Wt[(size_t)lcol[iA + k] * 8 + sub];
        ushort4 wB = Wt[(size_t)lcol[iB + k] * 8 + sub];
        accA.x += bf16_to_f32(wA.x); accA.y += bf16_to_f32(wA.y);
        accA.z += bf16_to_f32(wA.z); accA.w += bf16_to_f32(wA.w);
        accB.x += bf16_to_f32(wB.x); accB.y += bf16_to_f32(wB.y);
        accB.z += bf16_to_f32(wB.z); accB.w += bf16_to_f32(wB.w);
    }
    iA += nPair; iB += nPair;
    for (; iA < eA; iA++) {
        ushort4 w = Wt[(size_t)lcol[iA] * 8 + sub];
        accA.x += bf16_to_f32(w.x); accA.y += bf16_to_f32(w.y);
        accA.z += bf16_to_f32(w.z); accA.w += bf16_to_f32(w.w);
    }
    for (; iB < eB; iB++) {
        ushort4 w = Wt[(size_t)lcol[iB] * 8 + sub];
        accB.x += bf16_to_f32(w.x); accB.y += bf16_to_f32(w.y);
        accB.z += bf16_to_f32(w.z); accB.w += bf16_to_f32(w.w);
    }
    if (vA) ((float4*)out)[(size_t)outA * 8 + sub] = accA;
    if (vB) ((float4*)out)[(size_t)outB * 8 + sub] = accB;
}

extern "C" void kernel_launch(void* const* d_in, const int* in_sizes, int n_in,
                              void* d_out, int out_size, void* d_ws, size_t ws_size,
                              hipStream_t stream) {
    const int*   edge = (const int*)d_in[0];     // [2, NUM_EDGES] int32
    const float* W    = (const float*)d_in[1];   // [32, NUM_NODES]
    const float* b    = (const float*)d_in[2];   // [32]
    float* out = (float*)d_out;                  // [NUM_NODES, 32]

    // workspace: partmin @0 (1000B) | bcount @1024 (3132B) | Wt @8192 (6.4MB bf16) | bin @6422528 (16.0MB)
    char* ws = (char*)d_ws;
    int*          partmin = (int*)ws;
    int*          bcount  = (int*)(ws + 1024);
    ushort4*      Wt      = (ushort4*)(ws + 8192);
    unsigned int* bin     = (unsigned int*)(ws + 6422528);

    hipMemsetAsync(bcount, 0, NBG * sizeof(int), stream);
    fused_pre<<<TRB + BINB, FTPB, 0, stream>>>(W, Wt, edge, partmin, bcount, bin);
    bucket_gather<<<GGRID, GTPB, 0, stream>>>(bin, bcount, partmin, Wt, b, out);
}

// Round 9
// 154.607 us; speedup vs baseline: 1.6712x; 1.0275x over previous
//
#include <hip/hip_runtime.h>

#define NUM_NODES 100000
#define OUT_CH 32
#define NUM_EDGES 3200000

// fine buckets: 128 raw rows each
#define RPB 128
#define NB 782                  // buckets with data: raw row <= 99999 -> bucket <= 781
#define NBKT 784                // bucket index space in the gather grid (bcount zeroed to here)
#define CAP2 5120               // mean 4096, sigma ~64 -> +16 sigma
// fused front-end (uniform 1024-thread blocks) -- round-3 form (measured <=48us)
#define FTPB 1024
#define TRB 782                 // 128-col transpose tiles: ceil(100000/128)
#define BINB 250
#define TILE 12800              // 250*12800 = 3.2M; runs/(block,bucket) ~16 -> full 64B lines
#define KPT 13                  // ceil(TILE/FTPB)
// gather: 2 blocks per bucket = one per CHANNEL-HALF, XCD-affine
#define GTPB 256
#define GGRID 1568              // bkt = ((bk>>3)<<2)|(bk&3), half = (bk>>2)&1  (XCD = bk&7)

// ext_vector types: __builtin_nontemporal_* accepts these (HIP_vector_type it does not)
typedef unsigned int uint4e  __attribute__((ext_vector_type(4)));
typedef float        float4e __attribute__((ext_vector_type(4)));

static __device__ __forceinline__ unsigned short f32_to_bf16_rne(float f) {
    unsigned u = __float_as_uint(f);
    unsigned r = u + 0x7FFFu + ((u >> 16) & 1u);
    return (unsigned short)(r >> 16);
}
static __device__ __forceinline__ float bf16_to_f32(unsigned short h) {
    return __uint_as_float(((unsigned)h) << 16);
}

// ---------------- fused front-end: transpose W->Wt(2 half-tables, bf16) || bin edges by RAW row ----------------
// Wt layout: [half][col][4 x ushort4] -- half h = channels 16h..16h+15, 32B per col per half.
// Physically separate 3.2MB tables so a gather block's working set is per-XCD L2-resident.
__global__ void __launch_bounds__(FTPB)
fused_pre(const float* __restrict__ W, ushort4* __restrict__ Wt,
          const int* __restrict__ edge, int* __restrict__ partmin,
          int* __restrict__ bcount, unsigned int* __restrict__ bin) {
    int bk = blockIdx.x;
    int t  = threadIdx.x;
    if (bk < TRB) {
        __shared__ float tile[32][129];
        int tx = t & 127, ty = t >> 7;          // 128 x 8 threads, 4 sweeps
        int colBase = bk * 128;
        int col = colBase + tx;
        if (col < NUM_NODES) {
            #pragma unroll
            for (int k = 0; k < 4; k++) {
                int c = ty + 8 * k;
                tile[c][tx] = W[(size_t)c * NUM_NODES + col];
            }
        }
        __syncthreads();
        int lc = t >> 3, q = t & 7;             // q = channel quad 0..7
        int ocol = colBase + lc;
        if (ocol < NUM_NODES) {
            ushort4 o;
            o.x = f32_to_bf16_rne(tile[q * 4 + 0][lc]);
            o.y = f32_to_bf16_rne(tile[q * 4 + 1][lc]);
            o.z = f32_to_bf16_rne(tile[q * 4 + 2][lc]);
            o.w = f32_to_bf16_rne(tile[q * 4 + 3][lc]);
            // half = q>>2, quad-within-half = q&3
            Wt[(size_t)(q >> 2) * (NUM_NODES * 4) + (size_t)ocol * 4 + (q & 3)] = o;
        }
    } else {
        int mb = bk - TRB;
        __shared__ int cnt[NB];
        __shared__ int cur[NB];
        __shared__ int wm[16];
        for (int i = t; i < NB; i += FTPB) cnt[i] = 0;
        __syncthreads();
        int base = mb * TILE;
        unsigned int ent[KPT];
        int bb[KPT];
        int rm = 0x7fffffff;
        #pragma unroll
        for (int k = 0; k < KPT; k++) {
            int o = k * FTPB + t;
            bb[k] = -1;
            if (o < TILE) {
                int e = base + o;               // coalesced
                int r = edge[e];
                int c = edge[NUM_EDGES + e];
                rm = min(rm, r);
                int b = r >> 7;
                bb[k]  = b;
                ent[k] = ((unsigned int)(r & 127) << 17) | (unsigned int)c;
                atomicAdd(&cnt[b], 1);
            }
        }
        #pragma unroll
        for (int off = 32; off > 0; off >>= 1) rm = min(rm, __shfl_down(rm, off, 64));
        if ((t & 63) == 0) wm[t >> 6] = rm;
        __syncthreads();                        // cnt + wm complete
        if (t == 0) {
            int m = wm[0];
            #pragma unroll
            for (int w = 1; w < 16; w++) m = min(m, wm[w]);
            partmin[mb] = m;                    // plain store, distinct address per block
        }
        // one global reservation per (block, bucket): runs ~16 -> full 64B lines
        for (int i = t; i < NB; i += FTPB)
            cur[i] = cnt[i] ? atomicAdd(&bcount[i], cnt[i]) : 0;
        __syncthreads();
        #pragma unroll
        for (int k = 0; k < KPT; k++) {
            if (bb[k] >= 0) {
                int pos = atomicAdd(&cur[bb[k]], 1);
                if (pos < CAP2) bin[(size_t)bb[k] * CAP2 + pos] = ent[k];
            }
        }
    }
}

// ---------------- per-(bucket, channel-half) gather: row-CSR in LDS + L2-resident Wt-half ----------------
__global__ void __launch_bounds__(GTPB)
bucket_gather(const unsigned int* __restrict__ bin, const int* __restrict__ bcount,
              const int* __restrict__ partmin,
              const ushort4* __restrict__ Wt, const float* __restrict__ b,
              float* __restrict__ out) {
    __shared__ int cnt[RPB];
    __shared__ int cur[RPB];
    __shared__ int rowstart[RPB];
    __shared__ int scn[RPB];
    __shared__ int lcol[CAP2];
    __shared__ int wmin[4];
    __shared__ int rminS;

    int t  = threadIdx.x;
    int bk = blockIdx.x;
    int bkt  = ((bk >> 3) << 2) | (bk & 3);   // 0..783
    int half = (bk >> 2) & 1;                 // XCDs 0-3 -> half 0, XCDs 4-7 -> half 1

    // reduce the 250 per-block row-mins (overlapped with setup)
    int pm = (t < BINB) ? partmin[t] : 0x7fffffff;
    #pragma unroll
    for (int off = 32; off > 0; off >>= 1) pm = min(pm, __shfl_down(pm, off, 64));
    if ((t & 63) == 0) wmin[t >> 6] = pm;

    int n = (bkt < NB) ? bcount[bkt] : 0;
    if (n > CAP2) n = CAP2;
    const unsigned int* mybin = bin + (size_t)bkt * CAP2;

    if (t < RPB) cnt[t] = 0;
    __syncthreads();
    if (t == 0)
        rminS = min(min(wmin[0], wmin[1]), min(wmin[2], wmin[3]));

    // pass 1: count per row (uint4-vectorized nontemporal bin reads)
    int n4 = n >> 2;
    const uint4e* mybin4 = (const uint4e*)mybin;
    for (int i = t; i < n4; i += GTPB) {
        uint4e p = __builtin_nontemporal_load(&mybin4[i]);
        atomicAdd(&cnt[p.x >> 17], 1);
        atomicAdd(&cnt[p.y >> 17], 1);
        atomicAdd(&cnt[p.z >> 17], 1);
        atomicAdd(&cnt[p.w >> 17], 1);
    }
    for (int i = (n4 << 2) + t; i < n; i += GTPB) {
        unsigned int p = __builtin_nontemporal_load(&mybin[i]);
        atomicAdd(&cnt[p >> 17], 1);
    }
    __syncthreads();

    // inclusive scan over 128 row counts
    if (t < RPB) scn[t] = cnt[t];
    __syncthreads();
    for (int off = 1; off < RPB; off <<= 1) {
        int v = (t < RPB && t >= off) ? scn[t - off] : 0;
        __syncthreads();
        if (t < RPB) scn[t] += v;
        __syncthreads();
    }
    if (t < RPB) {
        int rs = scn[t] - cnt[t];
        rowstart[t] = rs;
        cur[t] = rs;
    }
    __syncthreads();

    // pass 2: scatter cols into LDS CSR (rows contiguous; order within row arbitrary)
    for (int i = t; i < n4; i += GTPB) {
        uint4e p = __builtin_nontemporal_load(&mybin4[i]);
        int p0 = atomicAdd(&cur[p.x >> 17], 1); lcol[p0] = p.x & 0x1FFFF;
        int p1 = atomicAdd(&cur[p.y >> 17], 1); lcol[p1] = p.y & 0x1FFFF;
        int p2 = atomicAdd(&cur[p.z >> 17], 1); lcol[p2] = p.z & 0x1FFFF;
        int p3 = atomicAdd(&cur[p.w >> 17], 1); lcol[p3] = p.w & 0x1FFFF;
    }
    for (int i = (n4 << 2) + t; i < n; i += GTPB) {
        unsigned int p = __builtin_nontemporal_load(&mybin[i]);
        int pos = atomicAdd(&cur[p >> 17], 1);
        lcol[pos] = p & 0x1FFFF;
    }
    __syncthreads();

    // gather-sum: 4 lanes/row (16 ch), 2 rows/thread, 2x k-batch (4 loads in flight)
    int g   = t >> 2;       // 0..63
    int sub = t & 3;
    const ushort4* Wth = Wt + (size_t)half * (NUM_NODES * 4);
    float4 bias = ((const float4*)b)[half * 4 + sub];
    int rmin = rminS;
    int lrA = g, lrB = g + 64;
    int outA = bkt * RPB + lrA - rmin;
    int outB = bkt * RPB + lrB - rmin;
    bool vA = (unsigned)outA < NUM_NODES;
    bool vB = (unsigned)outB < NUM_NODES;
    int iA = rowstart[lrA], eA = iA + cnt[lrA];
    int iB = rowstart[lrB], eB = iB + cnt[lrB];
    if (!vA) { iA = eA = 0; }
    if (!vB) { iB = eB = 0; }
    float4 accA = bias, accB = bias;
    int nPair = min(eA - iA, eB - iB);
    int k = 0;
    for (; k + 2 <= nPair; k += 2) {
        int cA0 = lcol[iA + k], cA1 = lcol[iA + k + 1];
        int cB0 = lcol[iB + k], cB1 = lcol[iB + k + 1];
        ushort4 a0 = Wth[(size_t)cA0 * 4 + sub];
        ushort4 a1 = Wth[(size_t)cA1 * 4 + sub];
        ushort4 b0 = Wth[(size_t)cB0 * 4 + sub];
        ushort4 b1 = Wth[(size_t)cB1 * 4 + sub];
        accA.x += bf16_to_f32(a0.x) + bf16_to_f32(a1.x);
        accA.y += bf16_to_f32(a0.y) + bf16_to_f32(a1.y);
        accA.z += bf16_to_f32(a0.z) + bf16_to_f32(a1.z);
        accA.w += bf16_to_f32(a0.w) + bf16_to_f32(a1.w);
        accB.x += bf16_to_f32(b0.x) + bf16_to_f32(b1.x);
        accB.y += bf16_to_f32(b0.y) + bf16_to_f32(b1.y);
        accB.z += bf16_to_f32(b0.z) + bf16_to_f32(b1.z);
        accB.w += bf16_to_f32(b0.w) + bf16_to_f32(b1.w);
    }
    for (; k < nPair; k++) {
        ushort4 wA = Wth[(size_t)lcol[iA + k] * 4 + sub];
        ushort4 wB = Wth[(size_t)lcol[iB + k] * 4 + sub];
        accA.x += bf16_to_f32(wA.x); accA.y += bf16_to_f32(wA.y);
        accA.z += bf16_to_f32(wA.z); accA.w += bf16_to_f32(wA.w);
        accB.x += bf16_to_f32(wB.x); accB.y += bf16_to_f32(wB.y);
        accB.z += bf16_to_f32(wB.z); accB.w += bf16_to_f32(wB.w);
    }
    iA += nPair; iB += nPair;
    for (; iA < eA; iA++) {
        ushort4 w = Wth[(size_t)lcol[iA] * 4 + sub];
        accA.x += bf16_to_f32(w.x); accA.y += bf16_to_f32(w.y);
        accA.z += bf16_to_f32(w.z); accA.w += bf16_to_f32(w.w);
    }
    for (; iB < eB; iB++) {
        ushort4 w = Wth[(size_t)lcol[iB] * 4 + sub];
        accB.x += bf16_to_f32(w.x); accB.y += bf16_to_f32(w.y);
        accB.z += bf16_to_f32(w.z); accB.w += bf16_to_f32(w.w);
    }
    // out row = 128B; this half's 4 lanes write one full 64B line (no RFO), nontemporal
    float4e oA = { accA.x, accA.y, accA.z, accA.w };
    float4e oB = { accB.x, accB.y, accB.z, accB.w };
    if (vA) __builtin_nontemporal_store(oA, &((float4e*)out)[(size_t)outA * 8 + half * 4 + sub]);
    if (vB) __builtin_nontemporal_store(oB, &((float4e*)out)[(size_t)outB * 8 + half * 4 + sub]);
}

extern "C" void kernel_launch(void* const* d_in, const int* in_sizes, int n_in,
                              void* d_out, int out_size, void* d_ws, size_t ws_size,
                              hipStream_t stream) {
    const int*   edge = (const int*)d_in[0];     // [2, NUM_EDGES] int32
    const float* W    = (const float*)d_in[1];   // [32, NUM_NODES]
    const float* b    = (const float*)d_in[2];   // [32]
    float* out = (float*)d_out;                  // [NUM_NODES, 32]

    // workspace: partmin @0 (1000B) | bcount @1024 (3136B) | Wt @8192 (6.4MB = 2 x 3.2MB halves) | bin @6422528 (16.0MB)
    char* ws = (char*)d_ws;
    int*          partmin = (int*)ws;
    int*          bcount  = (int*)(ws + 1024);
    ushort4*      Wt      = (ushort4*)(ws + 8192);
    unsigned int* bin     = (unsigned int*)(ws + 6422528);

    hipMemsetAsync(bcount, 0, NBKT * sizeof(int), stream);
    fused_pre<<<TRB + BINB, FTPB, 0, stream>>>(W, Wt, edge, partmin, bcount, bin);
    bucket_gather<<<GGRID, GTPB, 0, stream>>>(bin, bcount, partmin, Wt, b, out);
}